// Round 3
// baseline (194.077 us; speedup 1.0000x reference)
//
#include <hip/hip_runtime.h>
#include <hip/hip_bf16.h>
#include <limits.h>

typedef __attribute__((ext_vector_type(8))) short short8;
typedef __attribute__((ext_vector_type(4))) float f32x4;

#define NN 8000
#define NCOL 4096      // 8*512 merged columns
#define KBINS 352      // NEST-1 == TOTAL_BINS
#define QPAD 640       // 583 padded
#define QH 160         // q rows per block (4 q-blocks)
#define BN 128         // cols per block
#define KC 4           // k chunks
#define NTILE 125      // 8000/64 k-tiles of 64
#define CUTQ 4
#define T_ 512

#define GLL16(g, l) __builtin_amdgcn_global_load_lds( \
    (const __attribute__((address_space(1))) unsigned int*)(g), \
    (__attribute__((address_space(3))) unsigned int*)(l), 16, 0, 0)

static __device__ __forceinline__ ushort bfc(float f){
  __hip_bfloat16 h = __float2bfloat16(f);
  return *reinterpret_cast<ushort*>(&h);
}

// cosg[kt][q][slot-swizzled 64]: bf16(cos(2pi*((q*n)%8000)/8000)), 0 for pad rows.
// 8-bf16 slot s8 stored at s8 ^ (q&7)  -> conflict-free ds_read_b128 later.
__global__ void gen_cos_k(ushort* __restrict__ cosg, int HQI){
  int n = blockIdx.x*256 + threadIdx.x;
  int q = blockIdx.y;
  if (n >= NN) return;
  float v = 0.f;
  if (q < HQI){
    int m = (q*n) % NN;                            // exact integer angle reduction
    v = cosf((float)m * 7.8539816339744831e-4f);   // 2*pi/8000
  }
  int kt = n >> 6, s8 = (n >> 3) & 7, e = n & 7;
  cosg[(size_t)kt*(QPAD*64) + (size_t)q*64 + (((s8 ^ (q & 7)) << 3) | e)] = bfc(v);
}

// nonzero-support scan of a band matrix row -> [lo, hi)
__global__ void bounds_k(const float* __restrict__ W, int width,
                         int* __restrict__ lo, int* __restrict__ hi){
  __shared__ int slo, shi;
  int r = blockIdx.x;
  if (threadIdx.x==0){ slo = INT_MAX; shi = -1; }
  __syncthreads();
  int mylo = INT_MAX, myhi = -1;
  for (int c = threadIdx.x; c < width; c += 256){
    if (W[(size_t)r*width + c] != 0.f){ if (c < mylo) mylo = c; if (c > myhi) myhi = c; }
  }
  atomicMin(&slo, mylo); atomicMax(&shi, myhi);
  __syncthreads();
  if (threadIdx.x==0){ lo[r] = slo; hi[r] = shi + 1; }
}

// part[kc][col][q] = sum_{k in chunk} dx[col][k]*cos[q][k]
// Block: 160q x 128col, BK=64, double-buffered LDS, 2-phase pipeline (stage t+1 || compute t).
// 8 waves (2 q-waves x 4 col-waves), wave tile 80q x 32col (5x2 frags, 20 MFMA/step).
__global__ __launch_bounds__(512, 4) void gemm_k(const float* __restrict__ dx,
                                                 const ushort* __restrict__ cosg,
                                                 float* __restrict__ part){
  __shared__ ushort As[2][QH*64];    // cos tiles, 20 KB each, slot-swizzled
  __shared__ ushort Bs[2][BN*64];    // dx tiles bf16, 16 KB each, slot-swizzled
  int tid = threadIdx.x;
  int nb = blockIdx.x, qh = blockIdx.y, kc = blockIdx.z;
  int lane = tid & 63, widx = tid >> 6;
  int wm = widx & 1, wn = widx >> 1;
  int lrow = lane & 15, lk = lane >> 4;
  int kt0 = kc*32, ktE = (kt0 + 32 < NTILE) ? kt0 + 32 : NTILE;   // 32/32/32/29

  // dx staging: 4 threads/row, 16 floats each -> 16 bf16 = 2 ds_write_b128
  int brow = tid >> 2, bfo = (tid & 3) << 4;
  const float* dxp = dx + (size_t)(nb*BN + brow)*NN + bfo;
  int s8a = (tid & 3) << 1;
  const int bo0 = brow*64 + ((s8a ^ (brow & 7)) << 3);
  const int bo1 = brow*64 + (((s8a + 1) ^ (brow & 7)) << 3);
  // cos staging source base (pre-swizzled in cosg)
  const ushort* cg0 = cosg + (size_t)qh*(QH*64) + tid*8;

  f32x4 acc[5][2];
  #pragma unroll
  for (int a=0;a<5;a++){ acc[a][0] = (f32x4)0.f; acc[a][1] = (f32x4)0.f; }

  f32x4 d0,d1,d2,d3;
  {
    const float* p = dxp + (size_t)kt0*64;
    d0 = *(const f32x4*)p; d1 = *(const f32x4*)(p+4);
    d2 = *(const f32x4*)(p+8); d3 = *(const f32x4*)(p+12);
  }
  // prologue: stage tile kt0 into buffer 0
  {
    const ushort* cg = cg0 + (size_t)kt0*(QPAD*64);
    GLL16(cg,        &As[0][tid*8]);
    GLL16(cg + 4096, &As[0][4096 + tid*8]);
    if (tid < 256) GLL16(cg + 8192, &As[0][8192 + tid*8]);
    short8 a8, b8;
    a8[0]=(short)bfc(d0[0]); a8[1]=(short)bfc(d0[1]); a8[2]=(short)bfc(d0[2]); a8[3]=(short)bfc(d0[3]);
    a8[4]=(short)bfc(d1[0]); a8[5]=(short)bfc(d1[1]); a8[6]=(short)bfc(d1[2]); a8[7]=(short)bfc(d1[3]);
    b8[0]=(short)bfc(d2[0]); b8[1]=(short)bfc(d2[1]); b8[2]=(short)bfc(d2[2]); b8[3]=(short)bfc(d2[3]);
    b8[4]=(short)bfc(d3[0]); b8[5]=(short)bfc(d3[1]); b8[6]=(short)bfc(d3[2]); b8[7]=(short)bfc(d3[3]);
    *(short8*)(&Bs[0][bo0]) = a8;
    *(short8*)(&Bs[0][bo1]) = b8;
    if (kt0 + 1 < ktE){
      const float* p = dxp + (size_t)(kt0+1)*64;
      d0 = *(const f32x4*)p; d1 = *(const f32x4*)(p+4);
      d2 = *(const f32x4*)(p+8); d3 = *(const f32x4*)(p+12);
    }
  }
  __syncthreads();

  int cur = 0;
  for (int kt = kt0; kt < ktE; ++kt){
    // ---- stage tile kt+1 into buffer cur^1 (issued BEFORE compute of kt) ----
    if (kt + 1 < ktE){
      const ushort* cg = cg0 + (size_t)(kt+1)*(QPAD*64);
      ushort* an = &As[cur^1][0];
      GLL16(cg,        an + tid*8);
      GLL16(cg + 4096, an + 4096 + tid*8);
      if (tid < 256) GLL16(cg + 8192, an + 8192 + tid*8);
      short8 a8, b8;
      a8[0]=(short)bfc(d0[0]); a8[1]=(short)bfc(d0[1]); a8[2]=(short)bfc(d0[2]); a8[3]=(short)bfc(d0[3]);
      a8[4]=(short)bfc(d1[0]); a8[5]=(short)bfc(d1[1]); a8[6]=(short)bfc(d1[2]); a8[7]=(short)bfc(d1[3]);
      b8[0]=(short)bfc(d2[0]); b8[1]=(short)bfc(d2[1]); b8[2]=(short)bfc(d2[2]); b8[3]=(short)bfc(d2[3]);
      b8[4]=(short)bfc(d3[0]); b8[5]=(short)bfc(d3[1]); b8[6]=(short)bfc(d3[2]); b8[7]=(short)bfc(d3[3]);
      ushort* bn = &Bs[cur^1][0];
      *(short8*)(bn + bo0) = a8;
      *(short8*)(bn + bo1) = b8;
      if (kt + 2 < ktE){
        const float* p = dxp + (size_t)(kt+2)*64;
        d0 = *(const f32x4*)p; d1 = *(const f32x4*)(p+4);
        d2 = *(const f32x4*)(p+8); d3 = *(const f32x4*)(p+12);
      }
    }
    // ---- compute tile kt from buffer cur ----
    const ushort* Ac = &As[cur][0];
    const ushort* Bc = &Bs[cur][0];
    #pragma unroll
    for (int p=0;p<2;p++){
      short8 bfrag[5];
      #pragma unroll
      for (int a=0;a<5;a++){
        int row = wm*80 + 16*a + lrow;
        bfrag[a] = *(const short8*)(Ac + row*64 + ((((p<<2)|lk) ^ (row & 7)) << 3));
      }
      short8 afr[2];
      #pragma unroll
      for (int c=0;c<2;c++){
        int row = wn*32 + 16*c + lrow;
        afr[c] = *(const short8*)(Bc + row*64 + ((((p<<2)|lk) ^ (row & 7)) << 3));
      }
      #pragma unroll
      for (int a=0;a<5;a++){
        acc[a][0] = __builtin_amdgcn_mfma_f32_16x16x32_bf16(afr[0], bfrag[a], acc[a][0], 0,0,0);
        acc[a][1] = __builtin_amdgcn_mfma_f32_16x16x32_bf16(afr[1], bfrag[a], acc[a][1], 0,0,0);
      }
    }
    __syncthreads();          // next tile staged & all reads of cur done
    cur ^= 1;
  }

  // D layout: n(q) = lane&15, m(col) = 4*lk + r  -> part[kc][col][q], q contiguous
  float* pb = part + (size_t)kc*NCOL*QPAD;
  #pragma unroll
  for (int a=0;a<5;a++){
    int q = qh*QH + wm*80 + 16*a + lrow;
    #pragma unroll
    for (int c=0;c<2;c++){
      int col = nb*BN + wn*32 + 16*c + 4*lk;
      #pragma unroll
      for (int r=0;r<4;r++) pb[(size_t)(col+r)*QPAD + q] = acc[a][c][r];
    }
  }
}

// per (b,t) column: partial-sum + nonlinear -> band matmuls (Wf and Wq concurrently
// in disjoint thread ranges) -> harmonic gather
__global__ __launch_bounds__(768) void fuse_k(const float* __restrict__ dx,
        const float* __restrict__ Wf, const float* __restrict__ Wq,
        const float* __restrict__ part,
        const int* __restrict__ fLo, const int* __restrict__ fHi,
        const int* __restrict__ qLo, const int* __restrict__ qHi,
        float* __restrict__ out, int HFI, int HQI){
  __shared__ float xr[2304];
  __shared__ float yq[QPAD];
  __shared__ float tl0[KBINS];
  __shared__ float tlq[KBINS];
  int col = blockIdx.x;
  int b = col >> 9, t = col & 511;
  int tid = threadIdx.x;
  const float invs = 0.011180339887498949f;   // 1/sqrt(8000)

  for (int q = tid; q < HQI; q += 768){
    float s = 0.f;
    #pragma unroll
    for (int kc=0; kc<KC; kc++) s += part[(size_t)kc*NCOL*QPAD + (size_t)col*QPAD + q];
    s *= invs;
    float y = 0.f;
    if (q >= CUTQ && s > 0.f) y = powf(s, 0.6f);
    yq[q] = y;
  }
  for (int f = tid; f < HFI && f < 2304; f += 768) xr[f] = dx[(size_t)col*NN + f];
  __syncthreads();

  if (tid < KBINS){                      // Wf band rows
    int k = tid;
    float aF = 0.f;
    int lo = fLo[k], hx = fHi[k];
    for (int f = lo; f < hx; ++f) aF += Wf[(size_t)k*HFI + f] * xr[f];
    tl0[k] = aF;
  } else if (tid >= 384 && tid < 384 + KBINS){   // Wq band rows (concurrent)
    int k = tid - 384;
    float aQ = 0.f;
    int lo = qLo[k], hx = qHi[k];
    for (int q = lo; q < hx; ++q) aQ += Wq[(size_t)k*HQI + q] * yq[q];
    tlq[k] = aQ;
  }
  __syncthreads();

  const int hids[6] = {0,48,76,96,111,124};   // argmin|CF - (k+1)*27.5|
  for (int u = tid; u < 12*KBINS; u += 768){
    int j = u / KBINS;
    int k = u - j*KBINS;
    int h = hids[(j < 6) ? j : j - 6];
    float v;
    if (j < 6) v = (k + h < KBINS) ? tl0[k + h] : 0.f;   // har_s: shift left, pad end
    else       v = (k >= h)        ? tlq[k - h] : 0.f;   // har_c: shift right, pad front
    out[(((size_t)b*12 + j)*T_ + t)*KBINS + k] = v;
  }
}

extern "C" void kernel_launch(void* const* d_in, const int* in_sizes, int n_in,
                              void* d_out, int out_size, void* d_ws, size_t ws_size,
                              hipStream_t stream){
  const float* dx = (const float*)d_in[0];
  const float* Wf = (const float*)d_in[1];
  const float* Wq = (const float*)d_in[2];
  int HFI = in_sizes[1] / KBINS;   // runtime-derived (banker's-rounding safe)
  int HQI = in_sizes[2] / KBINS;
  float* out = (float*)d_out;
  char* ws = (char*)d_ws;

  ushort* cosg = (ushort*)ws;
  size_t off = (size_t)NTILE*QPAD*64*2;                       // 10.24 MB
  float* part = (float*)(ws + off); off += (size_t)KC*NCOL*QPAD*4;   // 41.94 MB
  int* fLo = (int*)(ws+off); off += KBINS*4;
  int* fHi = (int*)(ws+off); off += KBINS*4;
  int* qLo = (int*)(ws+off); off += KBINS*4;
  int* qHi = (int*)(ws+off); off += KBINS*4;
  (void)n_in; (void)out_size; (void)ws_size;

  gen_cos_k<<<dim3((NN+255)/256, QPAD), 256, 0, stream>>>(cosg, HQI);
  bounds_k<<<KBINS, 256, 0, stream>>>(Wf, HFI, fLo, fHi);
  bounds_k<<<KBINS, 256, 0, stream>>>(Wq, HQI, qLo, qHi);
  gemm_k<<<dim3(NCOL/BN, QPAD/QH, KC), 512, 0, stream>>>(dx, cosg, part);
  fuse_k<<<NCOL, 768, 0, stream>>>(dx, Wf, Wq, part, fLo, fHi, qLo, qHi, out, HFI, HQI);
}

// Round 4
// 142.002 us; speedup vs baseline: 1.3667x; 1.3667x over previous
//
#include <hip/hip_runtime.h>
#include <hip/hip_bf16.h>
#include <limits.h>

typedef __attribute__((ext_vector_type(8))) short short8;
typedef __attribute__((ext_vector_type(4))) float f32x4;

#define NN 8000
#define NCOL 4096      // 8*512 merged columns
#define KBINS 352      // NEST-1 == TOTAL_BINS
#define QPAD 640       // 583 padded
#define QH 160         // q rows per block (4 q-blocks)
#define BN 128         // cols per block
#define KC 4           // k chunks
#define NTILE 125      // 8000/64 k-tiles of 64
#define CUTQ 4
#define T_ 512
#define WFB 64         // packed band width for W_freq (max measured support 62)
#define WQB 20         // packed band width for W_quef (max measured support ~16)

#define GLL16(g, l) __builtin_amdgcn_global_load_lds( \
    (const __attribute__((address_space(1))) unsigned int*)(g), \
    (__attribute__((address_space(3))) unsigned int*)(l), 16, 0, 0)

static __device__ __forceinline__ ushort bfc(float f){
  __hip_bfloat16 h = __float2bfloat16(f);
  return *reinterpret_cast<ushort*>(&h);
}

// cosg[kt][q][slot-swizzled 64]: bf16(cos(2pi*((q*n)%8000)/8000)), 0 for pad rows.
// 8-bf16 slot s8 stored at s8 ^ (q&7)  -> conflict-free ds_read_b128 later.
__global__ void gen_cos_k(ushort* __restrict__ cosg, int HQI){
  int n = blockIdx.x*256 + threadIdx.x;
  int q = blockIdx.y;
  if (n >= NN) return;
  float v = 0.f;
  if (q < HQI){
    int m = (q*n) % NN;                            // exact integer angle reduction
    v = cosf((float)m * 7.8539816339744831e-4f);   // 2*pi/8000
  }
  int kt = n >> 6, s8 = (n >> 3) & 7, e = n & 7;
  cosg[(size_t)kt*(QPAD*64) + (size_t)q*64 + (((s8 ^ (q & 7)) << 3) | e)] = bfc(v);
}

// nonzero-support scan of a band matrix row -> [lo, hi); empty rows -> [0,0)
__global__ void bounds_k(const float* __restrict__ W, int width,
                         int* __restrict__ lo, int* __restrict__ hi){
  __shared__ int slo, shi;
  int r = blockIdx.x;
  if (threadIdx.x==0){ slo = INT_MAX; shi = -1; }
  __syncthreads();
  int mylo = INT_MAX, myhi = -1;
  for (int c = threadIdx.x; c < width; c += 256){
    if (W[(size_t)r*width + c] != 0.f){ if (c < mylo) mylo = c; if (c > myhi) myhi = c; }
  }
  atomicMin(&slo, mylo); atomicMax(&shi, myhi);
  __syncthreads();
  if (threadIdx.x==0){
    if (shi < 0){ lo[r] = 0; hi[r] = 0; }           // empty row: safe base
    else        { lo[r] = slo; hi[r] = shi + 1; }
  }
}

// pack band matrix rows into fixed-width TRANSPOSED banded form: WT[j][r], j<bw
__global__ void pack_k(const float* __restrict__ W, const int* __restrict__ lo,
                       const int* __restrict__ hi, int width, int bw,
                       float* __restrict__ WT){
  int r = blockIdx.x;
  int l = lo[r], h = hi[r];
  for (int j = threadIdx.x; j < bw; j += 64){
    float v = 0.f;
    if (l + j < h) v = W[(size_t)r*width + l + j];
    WT[(size_t)j*KBINS + r] = v;
  }
}

// part[kc][col][q] = sum_{k in chunk} dx[col][k]*cos[q][k]
// Block: 160q x 128col, BK=64, double-buffered LDS, 2-phase pipeline (stage t+1 || compute t).
// 8 waves (2 q-waves x 4 col-waves), wave tile 80q x 32col (5x2 frags, 20 MFMA/step).
__global__ __launch_bounds__(512, 4) void gemm_k(const float* __restrict__ dx,
                                                 const ushort* __restrict__ cosg,
                                                 float* __restrict__ part){
  __shared__ ushort As[2][QH*64];    // cos tiles, 20 KB each, slot-swizzled
  __shared__ ushort Bs[2][BN*64];    // dx tiles bf16, 16 KB each, slot-swizzled
  int tid = threadIdx.x;
  int nb = blockIdx.x, qh = blockIdx.y, kc = blockIdx.z;
  int lane = tid & 63, widx = tid >> 6;
  int wm = widx & 1, wn = widx >> 1;
  int lrow = lane & 15, lk = lane >> 4;
  int kt0 = kc*32, ktE = (kt0 + 32 < NTILE) ? kt0 + 32 : NTILE;   // 32/32/32/29

  // dx staging: 4 threads/row, 16 floats each -> 16 bf16 = 2 ds_write_b128
  int brow = tid >> 2, bfo = (tid & 3) << 4;
  const float* dxp = dx + (size_t)(nb*BN + brow)*NN + bfo;
  int s8a = (tid & 3) << 1;
  const int bo0 = brow*64 + ((s8a ^ (brow & 7)) << 3);
  const int bo1 = brow*64 + (((s8a + 1) ^ (brow & 7)) << 3);
  // cos staging source base (pre-swizzled in cosg)
  const ushort* cg0 = cosg + (size_t)qh*(QH*64) + tid*8;

  f32x4 acc[5][2];
  #pragma unroll
  for (int a=0;a<5;a++){ acc[a][0] = (f32x4)0.f; acc[a][1] = (f32x4)0.f; }

  f32x4 d0,d1,d2,d3;
  {
    const float* p = dxp + (size_t)kt0*64;
    d0 = *(const f32x4*)p; d1 = *(const f32x4*)(p+4);
    d2 = *(const f32x4*)(p+8); d3 = *(const f32x4*)(p+12);
  }
  // prologue: stage tile kt0 into buffer 0
  {
    const ushort* cg = cg0 + (size_t)kt0*(QPAD*64);
    GLL16(cg,        &As[0][tid*8]);
    GLL16(cg + 4096, &As[0][4096 + tid*8]);
    if (tid < 256) GLL16(cg + 8192, &As[0][8192 + tid*8]);
    short8 a8, b8;
    a8[0]=(short)bfc(d0[0]); a8[1]=(short)bfc(d0[1]); a8[2]=(short)bfc(d0[2]); a8[3]=(short)bfc(d0[3]);
    a8[4]=(short)bfc(d1[0]); a8[5]=(short)bfc(d1[1]); a8[6]=(short)bfc(d1[2]); a8[7]=(short)bfc(d1[3]);
    b8[0]=(short)bfc(d2[0]); b8[1]=(short)bfc(d2[1]); b8[2]=(short)bfc(d2[2]); b8[3]=(short)bfc(d2[3]);
    b8[4]=(short)bfc(d3[0]); b8[5]=(short)bfc(d3[1]); b8[6]=(short)bfc(d3[2]); b8[7]=(short)bfc(d3[3]);
    *(short8*)(&Bs[0][bo0]) = a8;
    *(short8*)(&Bs[0][bo1]) = b8;
    if (kt0 + 1 < ktE){
      const float* p = dxp + (size_t)(kt0+1)*64;
      d0 = *(const f32x4*)p; d1 = *(const f32x4*)(p+4);
      d2 = *(const f32x4*)(p+8); d3 = *(const f32x4*)(p+12);
    }
  }
  __syncthreads();

  int cur = 0;
  for (int kt = kt0; kt < ktE; ++kt){
    // ---- stage tile kt+1 into buffer cur^1 (issued BEFORE compute of kt) ----
    if (kt + 1 < ktE){
      const ushort* cg = cg0 + (size_t)(kt+1)*(QPAD*64);
      ushort* an = &As[cur^1][0];
      GLL16(cg,        an + tid*8);
      GLL16(cg + 4096, an + 4096 + tid*8);
      if (tid < 256) GLL16(cg + 8192, an + 8192 + tid*8);
      short8 a8, b8;
      a8[0]=(short)bfc(d0[0]); a8[1]=(short)bfc(d0[1]); a8[2]=(short)bfc(d0[2]); a8[3]=(short)bfc(d0[3]);
      a8[4]=(short)bfc(d1[0]); a8[5]=(short)bfc(d1[1]); a8[6]=(short)bfc(d1[2]); a8[7]=(short)bfc(d1[3]);
      b8[0]=(short)bfc(d2[0]); b8[1]=(short)bfc(d2[1]); b8[2]=(short)bfc(d2[2]); b8[3]=(short)bfc(d2[3]);
      b8[4]=(short)bfc(d3[0]); b8[5]=(short)bfc(d3[1]); b8[6]=(short)bfc(d3[2]); b8[7]=(short)bfc(d3[3]);
      ushort* bn = &Bs[cur^1][0];
      *(short8*)(bn + bo0) = a8;
      *(short8*)(bn + bo1) = b8;
      if (kt + 2 < ktE){
        const float* p = dxp + (size_t)(kt+2)*64;
        d0 = *(const f32x4*)p; d1 = *(const f32x4*)(p+4);
        d2 = *(const f32x4*)(p+8); d3 = *(const f32x4*)(p+12);
      }
    }
    // ---- compute tile kt from buffer cur ----
    const ushort* Ac = &As[cur][0];
    const ushort* Bc = &Bs[cur][0];
    #pragma unroll
    for (int p=0;p<2;p++){
      short8 bfrag[5];
      #pragma unroll
      for (int a=0;a<5;a++){
        int row = wm*80 + 16*a + lrow;
        bfrag[a] = *(const short8*)(Ac + row*64 + ((((p<<2)|lk) ^ (row & 7)) << 3));
      }
      short8 afr[2];
      #pragma unroll
      for (int c=0;c<2;c++){
        int row = wn*32 + 16*c + lrow;
        afr[c] = *(const short8*)(Bc + row*64 + ((((p<<2)|lk) ^ (row & 7)) << 3));
      }
      #pragma unroll
      for (int a=0;a<5;a++){
        acc[a][0] = __builtin_amdgcn_mfma_f32_16x16x32_bf16(afr[0], bfrag[a], acc[a][0], 0,0,0);
        acc[a][1] = __builtin_amdgcn_mfma_f32_16x16x32_bf16(afr[1], bfrag[a], acc[a][1], 0,0,0);
      }
    }
    __syncthreads();          // next tile staged & all reads of cur done
    cur ^= 1;
  }

  // D layout: n(q) = lane&15, m(col) = 4*lk + r  -> part[kc][col][q], q contiguous
  float* pb = part + (size_t)kc*NCOL*QPAD;
  #pragma unroll
  for (int a=0;a<5;a++){
    int q = qh*QH + wm*80 + 16*a + lrow;
    #pragma unroll
    for (int c=0;c<2;c++){
      int col = nb*BN + wn*32 + 16*c + 4*lk;
      #pragma unroll
      for (int r=0;r<4;r++) pb[(size_t)(col+r)*QPAD + q] = acc[a][c][r];
    }
  }
}

// per (b,t) column: partial-sum + nonlinear -> fixed-width banded matvecs
// (coalesced, fully unrolled) -> harmonic gather
__global__ __launch_bounds__(384) void fuse_k(const float* __restrict__ dx,
        const float* __restrict__ part,
        const float* __restrict__ WfT, const float* __restrict__ WqT,
        const int* __restrict__ fLo, const int* __restrict__ qLo,
        float* __restrict__ out, int HFI, int HQI){
  __shared__ float xr[2304];
  __shared__ float yq[QPAD];
  __shared__ float tl0[KBINS];
  __shared__ float tlq[KBINS];
  int col = blockIdx.x;
  int b = col >> 9, t = col & 511;
  int tid = threadIdx.x;
  const float invs = 0.011180339887498949f;   // 1/sqrt(8000)

  for (int f = tid; f < 2304; f += 384) xr[f] = (f < HFI) ? dx[(size_t)col*NN + f] : 0.f;
  for (int q = tid; q < QPAD; q += 384){
    float y = 0.f;
    if (q < HQI){
      float s = 0.f;
      #pragma unroll
      for (int kc=0; kc<KC; kc++) s += part[(size_t)kc*NCOL*QPAD + (size_t)col*QPAD + q];
      s *= invs;
      if (q >= CUTQ && s > 0.f) y = powf(s, 0.6f);
    }
    yq[q] = y;
  }
  __syncthreads();

  if (tid < KBINS){
    int k = tid;
    int lo = fLo[k];
    float aF = 0.f;
    #pragma unroll
    for (int j=0;j<WFB;j++) aF += WfT[j*KBINS + k] * xr[lo + j];
    int ql = qLo[k];
    float aQ = 0.f;
    #pragma unroll
    for (int j=0;j<WQB;j++) aQ += WqT[j*KBINS + k] * yq[ql + j];
    tl0[k] = aF; tlq[k] = aQ;
  }
  __syncthreads();

  const int hids[6] = {0,48,76,96,111,124};   // argmin|CF - (k+1)*27.5|
  for (int u = tid; u < 12*KBINS; u += 384){
    int j = u / KBINS;
    int k = u - j*KBINS;
    int h = hids[(j < 6) ? j : j - 6];
    float v;
    if (j < 6) v = (k + h < KBINS) ? tl0[k + h] : 0.f;   // har_s: shift left, pad end
    else       v = (k >= h)        ? tlq[k - h] : 0.f;   // har_c: shift right, pad front
    out[(((size_t)b*12 + j)*T_ + t)*KBINS + k] = v;
  }
}

extern "C" void kernel_launch(void* const* d_in, const int* in_sizes, int n_in,
                              void* d_out, int out_size, void* d_ws, size_t ws_size,
                              hipStream_t stream){
  const float* dx = (const float*)d_in[0];
  const float* Wf = (const float*)d_in[1];
  const float* Wq = (const float*)d_in[2];
  int HFI = in_sizes[1] / KBINS;   // runtime-derived (banker's-rounding safe)
  int HQI = in_sizes[2] / KBINS;
  float* out = (float*)d_out;
  char* ws = (char*)d_ws;

  ushort* cosg = (ushort*)ws;
  size_t off = (size_t)NTILE*QPAD*64*2;                       // 10.24 MB
  float* part = (float*)(ws + off); off += (size_t)KC*NCOL*QPAD*4;   // 41.94 MB
  int* fLo = (int*)(ws+off); off += KBINS*4;
  int* fHi = (int*)(ws+off); off += KBINS*4;
  int* qLo = (int*)(ws+off); off += KBINS*4;
  int* qHi = (int*)(ws+off); off += KBINS*4;
  float* WfT = (float*)(ws+off); off += (size_t)WFB*KBINS*4;  // 90 KB
  float* WqT = (float*)(ws+off); off += (size_t)WQB*KBINS*4;  // 28 KB
  (void)n_in; (void)out_size; (void)ws_size;

  gen_cos_k<<<dim3((NN+255)/256, QPAD), 256, 0, stream>>>(cosg, HQI);
  bounds_k<<<KBINS, 256, 0, stream>>>(Wf, HFI, fLo, fHi);
  bounds_k<<<KBINS, 256, 0, stream>>>(Wq, HQI, qLo, qHi);
  pack_k<<<KBINS, 64, 0, stream>>>(Wf, fLo, fHi, HFI, WFB, WfT);
  pack_k<<<KBINS, 64, 0, stream>>>(Wq, qLo, qHi, HQI, WQB, WqT);
  gemm_k<<<dim3(NCOL/BN, QPAD/QH, KC), 512, 0, stream>>>(dx, cosg, part);
  fuse_k<<<NCOL, 384, 0, stream>>>(dx, part, WfT, WqT, fLo, qLo, out, HFI, HQI);
}

// Round 5
// 139.707 us; speedup vs baseline: 1.3892x; 1.0164x over previous
//
#include <hip/hip_runtime.h>
#include <hip/hip_bf16.h>
#include <limits.h>

typedef __attribute__((ext_vector_type(8))) short short8;
typedef __attribute__((ext_vector_type(4))) short short4v;
typedef __attribute__((ext_vector_type(4))) float f32x4;
typedef __attribute__((ext_vector_type(16))) float f32x16;

#define NN 8000
#define NCOL 4096      // 8*512 merged columns
#define KBINS 352      // NEST-1 == TOTAL_BINS
#define QPAD 640       // 583 padded
#define QH 320         // q rows per block (2 q-halves)
#define BN 256         // cols per block
#define KC 8           // k chunks (grid 16x2x8 = 256 blocks = 1/CU)
#define NTILE 125      // 8000/64 k-tiles of 64
#define CUTQ 4
#define T_ 512
#define WFB 64         // packed band width for W_freq
#define WQB 20         // packed band width for W_quef

#define GLL16(g, l) __builtin_amdgcn_global_load_lds( \
    (const __attribute__((address_space(1))) unsigned int*)(g), \
    (__attribute__((address_space(3))) unsigned int*)(l), 16, 0, 0)

static __device__ __forceinline__ ushort bfc(float f){
  __hip_bfloat16 h = __float2bfloat16(f);
  return *reinterpret_cast<ushort*>(&h);
}
static __device__ __forceinline__ float b2f(ushort u){
  unsigned v = ((unsigned)u) << 16; float f; __builtin_memcpy(&f, &v, 4); return f;
}

// cosg[kt][q][slot-swizzled 64]: bf16(cos(2pi*((q*n)%8000)/8000)), 0 for pad rows.
// 8-bf16 slot s8 stored at s8 ^ (q&7)  -> conflict-free ds_read_b128 later.
__global__ void gen_cos_k(ushort* __restrict__ cosg, int HQI){
  int n = blockIdx.x*256 + threadIdx.x;
  int q = blockIdx.y;
  if (n >= NN) return;
  float v = 0.f;
  if (q < HQI){
    int m = (q*n) % NN;                            // exact integer angle reduction
    v = cosf((float)m * 7.8539816339744831e-4f);   // 2*pi/8000
  }
  int kt = n >> 6, s8 = (n >> 3) & 7, e = n & 7;
  cosg[(size_t)kt*(QPAD*64) + (size_t)q*64 + (((s8 ^ (q & 7)) << 3) | e)] = bfc(v);
}

// nonzero-support scan of a band matrix row -> [lo, hi); empty rows -> [0,0)
__global__ void bounds_k(const float* __restrict__ W, int width,
                         int* __restrict__ lo, int* __restrict__ hi){
  __shared__ int slo, shi;
  int r = blockIdx.x;
  if (threadIdx.x==0){ slo = INT_MAX; shi = -1; }
  __syncthreads();
  int mylo = INT_MAX, myhi = -1;
  for (int c = threadIdx.x; c < width; c += 256){
    if (W[(size_t)r*width + c] != 0.f){ if (c < mylo) mylo = c; if (c > myhi) myhi = c; }
  }
  atomicMin(&slo, mylo); atomicMax(&shi, myhi);
  __syncthreads();
  if (threadIdx.x==0){
    if (shi < 0){ lo[r] = 0; hi[r] = 0; }
    else        { lo[r] = slo; hi[r] = shi + 1; }
  }
}

// pack band matrix rows into fixed-width TRANSPOSED banded form: WT[j][r], j<bw
__global__ void pack_k(const float* __restrict__ W, const int* __restrict__ lo,
                       const int* __restrict__ hi, int width, int bw,
                       float* __restrict__ WT){
  int r = blockIdx.x;
  int l = lo[r], h = hi[r];
  for (int j = threadIdx.x; j < bw; j += 64){
    float v = 0.f;
    if (l + j < h) v = W[(size_t)r*width + l + j];
    WT[(size_t)j*KBINS + r] = v;
  }
}

// part[kc][col][q] (bf16) = sum_{k in chunk} dx[col][k]*cos[q][k]
// Block: 320q x 256col, BK=64, dbuf LDS (144KB, 1 block/CU), 8 waves (2q x 4col),
// wave tile 160q x 64col as 5x2 mfma_32x32x16 tiles (47 FLOP/LDS-byte).
__global__ __launch_bounds__(512, 2) void gemm_k(const float* __restrict__ dx,
                                                 const ushort* __restrict__ cosg,
                                                 ushort* __restrict__ part){
  __shared__ ushort As[2][QH*64];    // cos tiles, 40 KB each, slot-swizzled
  __shared__ ushort Bs[2][BN*64];    // dx tiles bf16, 32 KB each, slot-swizzled
  int tid = threadIdx.x;
  int nb = blockIdx.x, qh = blockIdx.y, kc = blockIdx.z;
  int lane = tid & 63, widx = tid >> 6;
  int wm = widx & 1, wn = widx >> 1;          // wm: q-half(160), wn: col-quarter(64)
  int l31 = lane & 31, lh = lane >> 5;
  int kt0 = kc*16, ktE = (kc < 7) ? kt0 + 16 : NTILE;   // 16 steps (13 last)

  // dx staging: per round i (8 rounds), wave covers 4 rows x 256B contiguous:
  // row = i*32 + widx*4 + (lane>>4), 16B at (lane&15)*16  -> coalesced 256B segments
  int srow = widx*4 + (lane >> 4);            // 0..31
  int sfo  = (lane & 15) * 4;                 // float offset within 64-k row
  // ds_write target: 4 floats -> 8 bf16? no: 4 floats -> b64 at sub-slot
  // k = sfo + e -> slot16 = sfo>>3? (16B slots of 8 bf16): slot = (lane&15)>>1, half = lane&1? 
  // careful: k = (lane&15)*4 + e, e<4 -> slot8 (8-bf16 slot) = k/8 = (lane&15)>>1, half = (lane&15)&1
  int slot16 = (lane & 15) >> 1, shalf = (lane & 15) & 1;
  // cos GLL source base
  const ushort* cg0 = cosg + (size_t)qh*(QH*64);

  f32x16 acc[5][2];
  #pragma unroll
  for (int a=0;a<5;a++){ acc[a][0] = (f32x16)0.f; acc[a][1] = (f32x16)0.f; }

  f32x4 d[8];
  #define DX_LOAD(kt_) { _Pragma("unroll") \
    for (int i=0;i<8;i++){ int row = i*32 + srow; \
      d[i] = *(const f32x4*)(dx + (size_t)(nb*BN + row)*NN + (size_t)(kt_)*64 + sfo); } }
  #define DX_WRITE(buf) { _Pragma("unroll") \
    for (int i=0;i<8;i++){ int row = i*32 + srow; \
      short4v s; s[0]=(short)bfc(d[i][0]); s[1]=(short)bfc(d[i][1]); \
                 s[2]=(short)bfc(d[i][2]); s[3]=(short)bfc(d[i][3]); \
      *(short4v*)(&Bs[buf][row*64 + (((slot16 ^ (row & 7)) << 3) | (shalf << 2))]) = s; } }
  #define COS_STAGE(kt_, buf) { const ushort* cg = cg0 + (size_t)(kt_)*(QPAD*64) + tid*8; \
    _Pragma("unroll") \
    for (int i=0;i<5;i++) GLL16(cg + i*4096, &As[buf][i*4096 + tid*8]); }

  // prologue: stage kt0 into buffer 0
  DX_LOAD(kt0);
  COS_STAGE(kt0, 0);
  DX_WRITE(0);
  __syncthreads();

  int cur = 0;
  for (int kt = kt0; kt < ktE; ++kt){
    if (kt + 1 < ktE){                 // issue next-tile loads BEFORE compute (T14)
      COS_STAGE(kt+1, cur^1);
      DX_LOAD(kt+1);
    }
    // ---- compute tile kt from buffer cur ----
    const ushort* Ac = &As[cur][0];
    const ushort* Bc = &Bs[cur][0];
    #pragma unroll
    for (int p=0;p<4;p++){             // 4 k=16 passes within BK=64
      short8 dfr[2];
      #pragma unroll
      for (int c=0;c<2;c++){
        int row = wn*64 + c*32 + l31;
        dfr[c] = *(const short8*)(Bc + row*64 + ((((p<<1)|lh) ^ (row & 7)) << 3));
      }
      short8 cfr[5];
      #pragma unroll
      for (int a=0;a<5;a++){
        int row = wm*160 + a*32 + l31;
        cfr[a] = *(const short8*)(Ac + row*64 + ((((p<<1)|lh) ^ (row & 7)) << 3));
      }
      #pragma unroll
      for (int a=0;a<5;a++){
        acc[a][0] = __builtin_amdgcn_mfma_f32_32x32x16_bf16(dfr[0], cfr[a], acc[a][0], 0,0,0);
        acc[a][1] = __builtin_amdgcn_mfma_f32_32x32x16_bf16(dfr[1], cfr[a], acc[a][1], 0,0,0);
      }
    }
    if (kt + 1 < ktE) DX_WRITE(cur^1); // write next dx tile after compute
    __syncthreads();                   // drains GLL vmcnt + ds writes
    cur ^= 1;
  }

  // D layout (32x32): n(q) = lane&31, m(col) = (r&3) + 8*(r>>2) + 4*(lane>>5)
  ushort* pb = part + (size_t)kc*NCOL*QPAD;
  #pragma unroll
  for (int a=0;a<5;a++){
    int q = qh*QH + wm*160 + a*32 + l31;
    #pragma unroll
    for (int c=0;c<2;c++){
      int colb = nb*BN + wn*64 + c*32 + 4*lh;
      #pragma unroll
      for (int r=0;r<16;r++){
        int col = colb + (r&3) + 8*(r>>2);
        pb[(size_t)col*QPAD + q] = bfc(acc[a][c][r]);
      }
    }
  }
}

// per (b,t) column: partial-sum + nonlinear -> fixed-width banded matvecs -> harmonic gather
__global__ __launch_bounds__(384) void fuse_k(const float* __restrict__ dx,
        const ushort* __restrict__ part,
        const float* __restrict__ WfT, const float* __restrict__ WqT,
        const int* __restrict__ fLo, const int* __restrict__ qLo,
        float* __restrict__ out, int HFI, int HQI){
  __shared__ float xr[2368];
  __shared__ float yq[QPAD];
  __shared__ float tl0[KBINS];
  __shared__ float tlq[KBINS];
  int col = blockIdx.x;
  int b = col >> 9, t = col & 511;
  int tid = threadIdx.x;
  const float invs = 0.011180339887498949f;   // 1/sqrt(8000)

  for (int f = tid; f < 2368; f += 384) xr[f] = (f < HFI) ? dx[(size_t)col*NN + f] : 0.f;
  const ushort* pc = part + (size_t)col*QPAD;
  for (int q = tid; q < QPAD; q += 384){
    float y = 0.f;
    if (q < HQI){
      float s = 0.f;
      #pragma unroll
      for (int kc=0; kc<KC; kc++) s += b2f(pc[(size_t)kc*NCOL*QPAD + q]);
      s *= invs;
      if (q >= CUTQ && s > 0.f) y = powf(s, 0.6f);
    }
    yq[q] = y;
  }
  __syncthreads();

  if (tid < KBINS){
    int k = tid;
    int lo = fLo[k];
    float aF = 0.f;
    #pragma unroll
    for (int j=0;j<WFB;j++) aF += WfT[j*KBINS + k] * xr[lo + j];
    int ql = qLo[k];
    float aQ = 0.f;
    #pragma unroll
    for (int j=0;j<WQB;j++) aQ += WqT[j*KBINS + k] * yq[ql + j];
    tl0[k] = aF; tlq[k] = aQ;
  }
  __syncthreads();

  const int hids[6] = {0,48,76,96,111,124};   // argmin|CF - (k+1)*27.5|
  for (int u = tid; u < 12*KBINS; u += 384){
    int j = u / KBINS;
    int k = u - j*KBINS;
    int h = hids[(j < 6) ? j : j - 6];
    float v;
    if (j < 6) v = (k + h < KBINS) ? tl0[k + h] : 0.f;   // har_s: shift left, pad end
    else       v = (k >= h)        ? tlq[k - h] : 0.f;   // har_c: shift right, pad front
    out[(((size_t)b*12 + j)*T_ + t)*KBINS + k] = v;
  }
}

extern "C" void kernel_launch(void* const* d_in, const int* in_sizes, int n_in,
                              void* d_out, int out_size, void* d_ws, size_t ws_size,
                              hipStream_t stream){
  const float* dx = (const float*)d_in[0];
  const float* Wf = (const float*)d_in[1];
  const float* Wq = (const float*)d_in[2];
  int HFI = in_sizes[1] / KBINS;   // runtime-derived (banker's-rounding safe)
  int HQI = in_sizes[2] / KBINS;
  float* out = (float*)d_out;
  char* ws = (char*)d_ws;

  ushort* cosg = (ushort*)ws;
  size_t off = (size_t)NTILE*QPAD*64*2;                        // 10.24 MB
  ushort* part = (ushort*)(ws + off); off += (size_t)KC*NCOL*QPAD*2;  // 41.94 MB (bf16)
  int* fLo = (int*)(ws+off); off += KBINS*4;
  int* fHi = (int*)(ws+off); off += KBINS*4;
  int* qLo = (int*)(ws+off); off += KBINS*4;
  int* qHi = (int*)(ws+off); off += KBINS*4;
  float* WfT = (float*)(ws+off); off += (size_t)WFB*KBINS*4;   // 90 KB
  float* WqT = (float*)(ws+off); off += (size_t)WQB*KBINS*4;   // 28 KB
  (void)n_in; (void)out_size; (void)ws_size;

  gen_cos_k<<<dim3((NN+255)/256, QPAD), 256, 0, stream>>>(cosg, HQI);
  bounds_k<<<KBINS, 256, 0, stream>>>(Wf, HFI, fLo, fHi);
  bounds_k<<<KBINS, 256, 0, stream>>>(Wq, HQI, qLo, qHi);
  pack_k<<<KBINS, 64, 0, stream>>>(Wf, fLo, fHi, HFI, WFB, WfT);
  pack_k<<<KBINS, 64, 0, stream>>>(Wq, qLo, qHi, HQI, WQB, WqT);
  gemm_k<<<dim3(NCOL/BN, QPAD/QH, KC), 512, 0, stream>>>(dx, cosg, part);
  fuse_k<<<NCOL, 384, 0, stream>>>(dx, part, WfT, WqT, fLo, qLo, out, HFI, HQI);
}

// Round 6
// 133.648 us; speedup vs baseline: 1.4521x; 1.0453x over previous
//
#include <hip/hip_runtime.h>
#include <hip/hip_bf16.h>
#include <limits.h>

typedef __attribute__((ext_vector_type(8))) short short8;
typedef __attribute__((ext_vector_type(4))) float f32x4;
typedef __attribute__((ext_vector_type(16))) float f32x16;

#define NN 8000
#define NCOL 4096      // 8*512 merged columns
#define KBINS 352      // NEST-1 == TOTAL_BINS
#define QPAD 640       // 583 padded
#define QH 320         // q rows per block (2 q-halves)
#define BN 256         // cols per block
#define KC 7           // k chunks (grid 16x2x7 = 224 blocks)
#define NTILE 63       // folded K: 4032 = 63 tiles of 64 (n>4000 zeroed)
#define KSTEP 9        // tiles per chunk: 63 = 7*9 exact
#define CUTQ 4
#define T_ 512
#define WFB 64         // packed band width for W_freq
#define WQB 20         // packed band width for W_quef

#define GLL16(g, l) __builtin_amdgcn_global_load_lds( \
    (const __attribute__((address_space(1))) unsigned int*)(g), \
    (__attribute__((address_space(3))) unsigned int*)(l), 16, 0, 0)

static __device__ __forceinline__ ushort bfc(float f){
  __hip_bfloat16 h = __float2bfloat16(f);
  return *reinterpret_cast<ushort*>(&h);
}
static __device__ __forceinline__ float b2f(ushort u){
  unsigned v = ((unsigned)u) << 16; float f; __builtin_memcpy(&f, &v, 4); return f;
}

// cosg[kt][q][slot-swizzled 64]: bf16(cos(2pi*((q*n)%8000)/8000)), 0 for pad rows.
// 8-bf16 slot s8 stored at s8 ^ (q&7)  -> conflict-free ds_read_b128 later.
// Only n < 4032 needed (folded K range).
__global__ void gen_cos_k(ushort* __restrict__ cosg, int HQI){
  int n = blockIdx.x*256 + threadIdx.x;
  int q = blockIdx.y;
  if (n >= NTILE*64) return;
  float v = 0.f;
  if (q < HQI){
    int m = (q*n) % NN;                            // exact integer angle reduction
    v = cosf((float)m * 7.8539816339744831e-4f);   // 2*pi/8000
  }
  int kt = n >> 6, s8 = (n >> 3) & 7, e = n & 7;
  cosg[(size_t)kt*(QPAD*64) + (size_t)q*64 + (((s8 ^ (q & 7)) << 3) | e)] = bfc(v);
}

// nonzero-support scan of a band matrix row -> [lo, hi); empty rows -> [0,0)
__global__ void bounds_k(const float* __restrict__ W, int width,
                         int* __restrict__ lo, int* __restrict__ hi){
  __shared__ int slo, shi;
  int r = blockIdx.x;
  if (threadIdx.x==0){ slo = INT_MAX; shi = -1; }
  __syncthreads();
  int mylo = INT_MAX, myhi = -1;
  for (int c = threadIdx.x; c < width; c += 256){
    if (W[(size_t)r*width + c] != 0.f){ if (c < mylo) mylo = c; if (c > myhi) myhi = c; }
  }
  atomicMin(&slo, mylo); atomicMax(&shi, myhi);
  __syncthreads();
  if (threadIdx.x==0){
    if (shi < 0){ lo[r] = 0; hi[r] = 0; }
    else        { lo[r] = slo; hi[r] = shi + 1; }
  }
}

// pack band matrix rows into fixed-width TRANSPOSED banded form: WT[j][r], j<bw
__global__ void pack_k(const float* __restrict__ W, const int* __restrict__ lo,
                       const int* __restrict__ hi, int width, int bw,
                       float* __restrict__ WT){
  int r = blockIdx.x;
  int l = lo[r], h = hi[r];
  for (int j = threadIdx.x; j < bw; j += 64){
    float v = 0.f;
    if (l + j < h) v = W[(size_t)r*width + l + j];
    WT[(size_t)j*KBINS + r] = v;
  }
}

// part[kc][col][q] (bf16) = sum_{k-tiles in chunk} xf[col][k]*cos[q][k]
// where xf is the symmetric fold of dx (computed on the fly in staging):
//   xf[0]=x[0]; xf[n]=x[n]+x[8000-n] (1<=n<4000); xf[4000]=x[4000]; xf[n>4000]=0
// Block: 320q x 256col, BK=64, dbuf LDS 144KB, 8 waves (2q x 4col),
// wave tile 160q x 64col as 5x2 mfma_32x32x16 tiles.
struct SR { f32x4 p0, p1, ma, mb; float ms; };

__global__ __launch_bounds__(512, 2) void gemm_k(const float* __restrict__ dx,
                                                 const ushort* __restrict__ cosg,
                                                 ushort* __restrict__ part){
  __shared__ ushort As[2][QH*64];    // cos tiles, 40 KB each, slot-swizzled
  __shared__ ushort Bs[2][BN*64];    // folded dx tiles bf16, 32 KB each, slot-swizzled
  int tid = threadIdx.x;
  int nb = blockIdx.x, qh = blockIdx.y, kc = blockIdx.z;
  int lane = tid & 63, widx = tid >> 6;
  int wm = widx & 1, wn = widx >> 1;          // wm: q-half(160), wn: col-quarter(64)
  int l31 = lane & 31, lh = lane >> 5;
  int kt0 = kc*KSTEP, ktE = kt0 + KSTEP;

  int srow = tid >> 3;                        // 0..63 (row within pass group)
  int sfo  = (tid & 7) * 8;                   // k offset (multiple of 8)

  // fold staging: per pass (4 passes of 64 rows), thread covers 8 k at one row.
  // mirror span 8000-n0-7..8000-n0 loaded as two aligned f32x4 + 1 scalar.
  #define LOADS(s_, kt_, pass_) { \
    int row_ = (pass_)*64 + srow; \
    const float* rp_ = dx + (size_t)(nb*BN + row_)*NN; \
    int n0_ = (kt_)*64 + sfo; \
    s_.p0 = *(const f32x4*)(rp_ + n0_); \
    s_.p1 = *(const f32x4*)(rp_ + n0_ + 4); \
    s_.ma = *(const f32x4*)(rp_ + 7996 - n0_); \
    s_.mb = *(const f32x4*)(rp_ + 7992 - n0_); \
    s_.ms = rp_[n0_ ? NN - n0_ : 0]; }

  #define WRITES(s_, kt_, pass_, buf_) { \
    int row_ = (pass_)*64 + srow; \
    int n0_ = (kt_)*64 + sfo; \
    float pr_[8] = {s_.p0[0],s_.p0[1],s_.p0[2],s_.p0[3],s_.p1[0],s_.p1[1],s_.p1[2],s_.p1[3]}; \
    float mi_[8] = {n0_ ? s_.ms : 0.f, s_.ma[3],s_.ma[2],s_.ma[1],s_.ma[0], s_.mb[3],s_.mb[2],s_.mb[1]}; \
    short8 o_; \
    _Pragma("unroll") \
    for (int e_=0;e_<8;e_++){ \
      int n_ = n0_ + e_; \
      float v_ = (n_ < 4000) ? pr_[e_] + mi_[e_] : ((n_ == 4000) ? pr_[e_] : 0.f); \
      o_[e_] = (short)bfc(v_); } \
    *(short8*)(&Bs[buf_][row_*64 + (((tid & 7) ^ (row_ & 7)) << 3)]) = o_; }

  #define COSG(kt_, buf_) { \
    const ushort* cg_ = cosg + (size_t)(kt_)*(QPAD*64) + (size_t)qh*(QH*64) + tid*8; \
    _Pragma("unroll") \
    for (int i_=0;i_<5;i_++) GLL16(cg_ + i_*4096, &As[buf_][i_*4096 + tid*8]); }

  f32x16 acc[5][2];
  #pragma unroll
  for (int a=0;a<5;a++){ acc[a][0] = (f32x16)0.f; acc[a][1] = (f32x16)0.f; }

  #define COMPUTE_HALF(h_, buf_) { \
    const ushort* Ac_ = &As[buf_][0]; const ushort* Bc_ = &Bs[buf_][0]; \
    _Pragma("unroll") \
    for (int p_=2*(h_); p_<2*(h_)+2; p_++){ \
      short8 dfr_[2]; \
      _Pragma("unroll") \
      for (int c_=0;c_<2;c_++){ int row_ = wn*64 + c_*32 + l31; \
        dfr_[c_] = *(const short8*)(Bc_ + row_*64 + ((((p_<<1)|lh) ^ (row_ & 7)) << 3)); } \
      short8 cfr_[5]; \
      _Pragma("unroll") \
      for (int a_=0;a_<5;a_++){ int row_ = wm*160 + a_*32 + l31; \
        cfr_[a_] = *(const short8*)(Ac_ + row_*64 + ((((p_<<1)|lh) ^ (row_ & 7)) << 3)); } \
      __builtin_amdgcn_s_setprio(1); \
      _Pragma("unroll") \
      for (int a_=0;a_<5;a_++){ \
        acc[a_][0] = __builtin_amdgcn_mfma_f32_32x32x16_bf16(dfr_[0], cfr_[a_], acc[a_][0], 0,0,0); \
        acc[a_][1] = __builtin_amdgcn_mfma_f32_32x32x16_bf16(dfr_[1], cfr_[a_], acc[a_][1], 0,0,0); } \
      __builtin_amdgcn_s_setprio(0); } }

  SR s0, s1;
  // prologue: stage tile kt0 into buffer 0
  LOADS(s0, kt0, 0); LOADS(s1, kt0, 1);
  COSG(kt0, 0);
  WRITES(s0, kt0, 0, 0); WRITES(s1, kt0, 1, 0);
  LOADS(s0, kt0, 2); LOADS(s1, kt0, 3);
  WRITES(s0, kt0, 2, 0); WRITES(s1, kt0, 3, 0);
  __syncthreads();

  int cur = 0;
  for (int kt = kt0; kt < ktE; ++kt){
    bool stg = (kt + 1 < ktE);
    if (stg){ COSG(kt+1, cur^1); LOADS(s0, kt+1, 0); LOADS(s1, kt+1, 1); }
    COMPUTE_HALF(0, cur);
    if (stg){ WRITES(s0, kt+1, 0, cur^1); WRITES(s1, kt+1, 1, cur^1);
              LOADS(s0, kt+1, 2); LOADS(s1, kt+1, 3); }
    COMPUTE_HALF(1, cur);
    if (stg){ WRITES(s0, kt+1, 2, cur^1); WRITES(s1, kt+1, 3, cur^1); }
    __syncthreads();                 // drains GLL vmcnt + ds writes; tiles visible
    cur ^= 1;
  }

  // D layout (32x32): n(q) = lane&31, m(col) = (r&3) + 8*(r>>2) + 4*(lane>>5)
  ushort* pb = part + (size_t)kc*NCOL*QPAD;
  #pragma unroll
  for (int a=0;a<5;a++){
    int q = qh*QH + wm*160 + a*32 + l31;
    #pragma unroll
    for (int c=0;c<2;c++){
      int colb = nb*BN + wn*64 + c*32 + 4*lh;
      #pragma unroll
      for (int r=0;r<16;r++){
        int col = colb + (r&3) + 8*(r>>2);
        pb[(size_t)col*QPAD + q] = bfc(acc[a][c][r]);
      }
    }
  }
}

// per (b,t) column: partial-sum + nonlinear -> fixed-width banded matvecs -> harmonic gather
__global__ __launch_bounds__(384) void fuse_k(const float* __restrict__ dx,
        const ushort* __restrict__ part,
        const float* __restrict__ WfT, const float* __restrict__ WqT,
        const int* __restrict__ fLo, const int* __restrict__ qLo,
        float* __restrict__ out, int HFI, int HQI){
  __shared__ float xr[2368];
  __shared__ float yq[QPAD];
  __shared__ float tl0[KBINS];
  __shared__ float tlq[KBINS];
  int col = blockIdx.x;
  int b = col >> 9, t = col & 511;
  int tid = threadIdx.x;
  const float invs = 0.011180339887498949f;   // 1/sqrt(8000)

  for (int f = tid; f < 2368; f += 384) xr[f] = (f < HFI) ? dx[(size_t)col*NN + f] : 0.f;
  const ushort* pc = part + (size_t)col*QPAD;
  for (int q = tid; q < QPAD; q += 384){
    float y = 0.f;
    if (q < HQI){
      float s = 0.f;
      #pragma unroll
      for (int kc=0; kc<KC; kc++) s += b2f(pc[(size_t)kc*NCOL*QPAD + q]);
      s *= invs;
      if (q >= CUTQ && s > 0.f) y = powf(s, 0.6f);
    }
    yq[q] = y;
  }
  __syncthreads();

  if (tid < KBINS){
    int k = tid;
    int lo = fLo[k];
    float aF = 0.f;
    #pragma unroll
    for (int j=0;j<WFB;j++) aF += WfT[j*KBINS + k] * xr[lo + j];
    int ql = qLo[k];
    float aQ = 0.f;
    #pragma unroll
    for (int j=0;j<WQB;j++) aQ += WqT[j*KBINS + k] * yq[ql + j];
    tl0[k] = aF; tlq[k] = aQ;
  }
  __syncthreads();

  const int hids[6] = {0,48,76,96,111,124};   // argmin|CF - (k+1)*27.5|
  for (int u = tid; u < 12*KBINS; u += 384){
    int j = u / KBINS;
    int k = u - j*KBINS;
    int h = hids[(j < 6) ? j : j - 6];
    float v;
    if (j < 6) v = (k + h < KBINS) ? tl0[k + h] : 0.f;   // har_s: shift left, pad end
    else       v = (k >= h)        ? tlq[k - h] : 0.f;   // har_c: shift right, pad front
    out[(((size_t)b*12 + j)*T_ + t)*KBINS + k] = v;
  }
}

extern "C" void kernel_launch(void* const* d_in, const int* in_sizes, int n_in,
                              void* d_out, int out_size, void* d_ws, size_t ws_size,
                              hipStream_t stream){
  const float* dx = (const float*)d_in[0];
  const float* Wf = (const float*)d_in[1];
  const float* Wq = (const float*)d_in[2];
  int HFI = in_sizes[1] / KBINS;   // runtime-derived (banker's-rounding safe)
  int HQI = in_sizes[2] / KBINS;
  float* out = (float*)d_out;
  char* ws = (char*)d_ws;

  ushort* cosg = (ushort*)ws;
  size_t off = (size_t)NTILE*QPAD*64*2;                        // 5.16 MB
  ushort* part = (ushort*)(ws + off); off += (size_t)KC*NCOL*QPAD*2;  // 36.7 MB (bf16)
  int* fLo = (int*)(ws+off); off += KBINS*4;
  int* fHi = (int*)(ws+off); off += KBINS*4;
  int* qLo = (int*)(ws+off); off += KBINS*4;
  int* qHi = (int*)(ws+off); off += KBINS*4;
  float* WfT = (float*)(ws+off); off += (size_t)WFB*KBINS*4;   // 90 KB
  float* WqT = (float*)(ws+off); off += (size_t)WQB*KBINS*4;   // 28 KB
  (void)n_in; (void)out_size; (void)ws_size;

  gen_cos_k<<<dim3((NTILE*64+255)/256, QPAD), 256, 0, stream>>>(cosg, HQI);
  bounds_k<<<KBINS, 256, 0, stream>>>(Wf, HFI, fLo, fHi);
  bounds_k<<<KBINS, 256, 0, stream>>>(Wq, HQI, qLo, qHi);
  pack_k<<<KBINS, 64, 0, stream>>>(Wf, fLo, fHi, HFI, WFB, WfT);
  pack_k<<<KBINS, 64, 0, stream>>>(Wq, qLo, qHi, HQI, WQB, WqT);
  gemm_k<<<dim3(NCOL/BN, QPAD/QH, KC), 512, 0, stream>>>(dx, cosg, part);
  fuse_k<<<NCOL, 384, 0, stream>>>(dx, part, WfT, WqT, fLo, qLo, out, HFI, HQI);
}